// Round 18
// baseline (145.055 us; speedup 1.0000x reference)
//
#include <hip/hip_runtime.h>
#include <math.h>

#define G    4      // segments per block
#define CAP  104    // max staged rows per group (~0.4% fallback)
#define SROW 112    // sA rows allocated (A-fragment tiles may read to 111)

typedef __attribute__((ext_vector_type(8))) short bf16x8;
typedef __attribute__((ext_vector_type(4))) float f32x4;

// ---------------------------------------------------------------------------
__global__ void k_segstarts(const int* __restrict__ map, int* __restrict__ starts,
                            int V, int S) {
    int i = blockIdx.x * blockDim.x + threadIdx.x;
    if (i >= V) return;
    int cur  = map[i];
    int prev = (i == 0) ? -1 : map[i - 1];
    for (int s = prev + 1; s <= cur; ++s) starts[s] = i;
    if (i == V - 1) {
        for (int s = cur + 1; s <= S; ++s) starts[s] = V;
    }
}

__device__ __forceinline__ unsigned f2bf_rte(float x) {          // RTNE -> top 16
    unsigned b = __float_as_uint(x);
    b += 0x7FFFu + ((b >> 16) & 1u);
    return b >> 16;
}
__device__ __forceinline__ float bfu_lo(unsigned u) {
    return __uint_as_float(u << 16);
}
__device__ __forceinline__ float bfu_hi(unsigned u) {
    return __uint_as_float(u & 0xFFFF0000u);
}

// fallback-path reduce: DPP adds + one ds_swizzle for xor16
template <int CTRL>
__device__ __forceinline__ float dpp_add(float v) {
    int t = __builtin_amdgcn_update_dpp(0, __float_as_int(v), CTRL, 0xF, 0xF, true);
    return v + __int_as_float(t);
}
__device__ __forceinline__ float red32_sum(float v) {
    v = dpp_add<0xB1>(v);
    v = dpp_add<0x4E>(v);
    v = dpp_add<0x141>(v);
    v = dpp_add<0x140>(v);
    v += __int_as_float(__builtin_amdgcn_ds_swizzle(__float_as_int(v), 0x401F));
    return v;
}

// ---------------------------------------------------------------------------
// k_prep: M = (Wk^T Wv) * LOG2E (q pre-scaled for exp2), Wt = Wo^T; both in
// MFMA B-fragment order (bf16): B col = lane&15, k = (lane>>4)*8 + t;
// ushort index = ((f*64 + lane)*8 + t), f = kt*8 + jt.
// ---------------------------------------------------------------------------
__global__ void k_prep(const float* __restrict__ Wk, const float* __restrict__ Wv,
                       const float* __restrict__ Wo,
                       unsigned short* __restrict__ Mpk,
                       unsigned short* __restrict__ Wpk) {
    const int i = blockIdx.x;     // k dim 0..127
    const int j = threadIdx.x;    // col  0..127
    float acc = 0.f;
#pragma unroll 8
    for (int h = 0; h < 128; ++h)
        acc += Wk[h * 128 + i] * Wv[h * 128 + j];
    acc *= 1.4426950408889634f;

    const int kt  = i >> 5;
    const int kg  = (i >> 3) & 3;
    const int t   = i & 7;
    const int jt  = j >> 4;
    const int l16 = j & 15;
    const int lane = kg * 16 + l16;
    const size_t idx = ((size_t)(kt * 8 + jt) * 64 + lane) * 8 + t;
    Mpk[idx] = (unsigned short)f2bf_rte(acc);
    Wpk[idx] = (unsigned short)f2bf_rte(Wo[j * 128 + i]);
}

// pack 8 consecutive fp32 -> bf16x8 (truncation)
__device__ __forceinline__ bf16x8 pack_a8(const float* p) {
    union { unsigned u[4]; bf16x8 v; } r;
    const float4 f0 = *(const float4*)p;
    const float4 f1 = *(const float4*)(p + 4);
    r.u[0] = (__float_as_uint(f0.y) & 0xFFFF0000u) | (__float_as_uint(f0.x) >> 16);
    r.u[1] = (__float_as_uint(f0.w) & 0xFFFF0000u) | (__float_as_uint(f0.z) >> 16);
    r.u[2] = (__float_as_uint(f1.y) & 0xFFFF0000u) | (__float_as_uint(f1.x) >> 16);
    r.u[3] = (__float_as_uint(f1.w) & 0xFFFF0000u) | (__float_as_uint(f1.z) >> 16);
    return r.v;
}

// swizzled within-row uint offset for sA
__device__ __forceinline__ int swz(int row, int uoff) {
    return uoff ^ ((row & 7) << 2);
}

// ---------------------------------------------------------------------------
// k_main: bf16 E staged once in LDS (XOR-swizzled rows); MFMA for qGEMM,
// SCORES, and outGEMM; slim VALU loops for mean and weighted-sum.
// Phases: stage -B1- mean -B2- qGEMM -B3- scoresMFMA -B3a- exp2 -B3b-
//         wsum -B4- outGEMM.
// sS is indexed by GROUP row (0..nrows-1); wsum reads sS[w][off + rp].
// ---------------------------------------------------------------------------
__global__ __launch_bounds__(256, 4) void k_main(
    const float* __restrict__ E, const int* __restrict__ starts,
    const unsigned short* __restrict__ Mpk, const unsigned short* __restrict__ Wpk,
    float* __restrict__ out, int V, int S)
{
    __shared__ unsigned sA[SROW][64];  // bf16-packed rows, swizzled (28.7 KB)
    __shared__ float    sE[G][128];    // ebar, later etilde (2 KB)
    __shared__ float    sQ[G][128];    // q (2 KB)
    __shared__ float    sS[G][SROW];   // scores -> exp'd weights (1.8 KB)

    const int tid  = threadIdx.x;
    const int w    = tid >> 6;       // wave id = local segment id
    const int lane = tid & 63;
    const int s0   = blockIdx.x * G;

    const int se    = min(s0 + G, S);
    const int gr0   = starts[s0];
    const int nrows = starts[se] - gr0;
    const bool staged = (nrows <= CAP);

    const int c  = lane & 31;        // column quad (sweeps)
    const int g  = lane >> 5;        // row parity (sweeps)

    // ---------------- stage: E rows -> swizzled bf16 LDS -------------------
    if (staged && nrows > 0) {
        const int q4 = tid & 31;
        const int rr = tid >> 5;                 // 0..7, stride 8
        const float* gp = E + (size_t)gr0 * 128 + q4 * 4;
#pragma unroll
        for (int b = 0; b < 3; ++b) {
            const int nb = (b == 2) ? 3 : 5;
            const int k0 = b * 5;
            float4 t[5];
            for (int k = 0; k < nb; ++k) {
                const int r = min(rr + (k0 + k) * 8, nrows - 1);   // clamp: dup
                t[k] = *(const float4*)(gp + (size_t)r * 128);
            }
            for (int k = 0; k < nb; ++k) {
                const int row = rr + (k0 + k) * 8;
                uint2 u;
                u.x = f2bf_rte(t[k].x) | (f2bf_rte(t[k].y) << 16);
                u.y = f2bf_rte(t[k].z) | (f2bf_rte(t[k].w) << 16);
                *(uint2*)&sA[row][swz(row, q4 * 2)] = u;           // dup unread
            }
        }
    }
    __syncthreads();                                            // B1

    // per-wave segment meta
    const int segi = s0 + w;
    int r0 = 0, n = 0, off = 0;
    if (segi < S) {
        r0  = starts[segi];
        n   = starts[segi + 1] - r0;
        off = r0 - gr0;
    }
    const int nfull = n & ~1;

    // ---------------- mean: ebar[w] ----------------------------------------
    {
        float4 sum = make_float4(0.f, 0.f, 0.f, 0.f);
        if (segi < S && n > 0) {
            if (staged) {
                for (int rp = 0; rp < nfull; rp += 2) {
                    const int row = off + rp + g;
                    const uint2 u = *(const uint2*)&sA[row][swz(row, c * 2)];
                    sum.x += bfu_lo(u.x); sum.y += bfu_hi(u.x);
                    sum.z += bfu_lo(u.y); sum.w += bfu_hi(u.y);
                }
                if ((n & 1) && g == 0) {
                    const int row = off + n - 1;
                    const uint2 u = *(const uint2*)&sA[row][swz(row, c * 2)];
                    sum.x += bfu_lo(u.x); sum.y += bfu_hi(u.x);
                    sum.z += bfu_lo(u.y); sum.w += bfu_hi(u.y);
                }
            } else {
                const float* bp = E + (size_t)r0 * 128 + c * 4;
                for (int rp = 0; rp < nfull; rp += 2) {
                    const float4 ev = *(const float4*)(bp + (size_t)(rp + g) * 128);
                    sum.x += ev.x; sum.y += ev.y; sum.z += ev.z; sum.w += ev.w;
                }
                if ((n & 1) && g == 0) {
                    const float4 ev = *(const float4*)(bp + (size_t)(n - 1) * 128);
                    sum.x += ev.x; sum.y += ev.y; sum.z += ev.z; sum.w += ev.w;
                }
            }
            sum.x += __shfl_xor(sum.x, 32);
            sum.y += __shfl_xor(sum.y, 32);
            sum.z += __shfl_xor(sum.z, 32);
            sum.w += __shfl_xor(sum.w, 32);
            const float inv = 1.0f / (float)n;
            sum.x *= inv; sum.y *= inv; sum.z *= inv; sum.w *= inv;
        }
        if (g == 0)
            *(float4*)&sE[w][c * 4] = sum;    // zeros when segi>=S or n==0
    }
    __syncthreads();                                            // B2

    // ---------------- q GEMM via MFMA: sQ = sE @ M -------------------------
    const int arow = lane & 15;       // A row / C col
    const int akg  = lane >> 4;       // k-group
    {
        f32x4 c0 = {0.f, 0.f, 0.f, 0.f};
        f32x4 c1 = {0.f, 0.f, 0.f, 0.f};
        const uint4* Bp = (const uint4*)Mpk;
#pragma unroll
        for (int kt = 0; kt < 4; ++kt) {
            const bf16x8 a = pack_a8(&sE[arow & 3][kt * 32 + akg * 8]);
            union { uint4 u; bf16x8 v; } b0, b1;
            b0.u = Bp[(size_t)(kt * 8 + 2 * w) * 64 + lane];
            b1.u = Bp[(size_t)(kt * 8 + 2 * w + 1) * 64 + lane];
            c0 = __builtin_amdgcn_mfma_f32_16x16x32_bf16(a, b0.v, c0, 0, 0, 0);
            c1 = __builtin_amdgcn_mfma_f32_16x16x32_bf16(a, b1.v, c1, 0, 0, 0);
        }
        if (akg == 0) {                       // C rows 0-3 live in lanes 0-15
#pragma unroll
            for (int r = 0; r < 4; ++r) {
                sQ[r][(2 * w) * 16 + arow]     = c0[r];
                sQ[r][(2 * w + 1) * 16 + arow] = c1[r];
            }
        }
    }
    __syncthreads();                                            // B3

    if (staged) {
        // ------------- scores via MFMA: sS[seg][grow] = E_grow . q_seg -----
        {
            const int Tall = (nrows + 15) >> 4;
            bf16x8 bq[4];
#pragma unroll
            for (int kt = 0; kt < 4; ++kt)
                bq[kt] = pack_a8(&sQ[arow & 3][kt * 32 + akg * 8]);
            for (int t = w; t < Tall; t += 4) {
                const int rbase = t * 16 + arow;          // A/E group row
                f32x4 cs = {0.f, 0.f, 0.f, 0.f};
#pragma unroll
                for (int kt = 0; kt < 4; ++kt) {
                    union { uint4 u; bf16x8 v; } a;
                    a.u = *(const uint4*)&sA[rbase][swz(rbase, kt * 16 + akg * 4)];
                    cs = __builtin_amdgcn_mfma_f32_16x16x32_bf16(a.v, bq[kt], cs, 0, 0, 0);
                }
                if (arow < 4) {                  // D col = segment = lane&15
#pragma unroll
                    for (int r = 0; r < 4; ++r)
                        sS[arow][t * 16 + akg * 4 + r] = cs[r];
                }
            }
        }
        __syncthreads();                                        // B3a

        // ------------- exp2 of all scores ----------------------------------
        for (int i = tid; i < G * SROW; i += 256) {
            sS[0][i] = exp2f(sS[0][i]);       // flat; pad garbage unused
        }
        __syncthreads();                                        // B3b

        // ------------- weighted sum: slim loop (GROUP-row indexed sS) ------
        {
            float4 acc = make_float4(0.f, 0.f, 0.f, 0.f);
            float Z = 0.f;
            if (segi < S && n > 0) {
                for (int rp = 0; rp < nfull; rp += 2) {
                    const int row = off + rp + g;
                    const uint2 u = *(const uint2*)&sA[row][swz(row, c * 2)];
                    const float wgt = sS[w][row];
                    Z += wgt;
                    acc.x += wgt * bfu_lo(u.x); acc.y += wgt * bfu_hi(u.x);
                    acc.z += wgt * bfu_lo(u.y); acc.w += wgt * bfu_hi(u.y);
                }
                if ((n & 1) && g == 0) {
                    const int row = off + n - 1;
                    const uint2 u = *(const uint2*)&sA[row][swz(row, c * 2)];
                    const float wgt = sS[w][row];
                    Z += wgt;
                    acc.x += wgt * bfu_lo(u.x); acc.y += wgt * bfu_hi(u.x);
                    acc.z += wgt * bfu_lo(u.y); acc.w += wgt * bfu_hi(u.y);
                }
                acc.x += __shfl_xor(acc.x, 32);
                acc.y += __shfl_xor(acc.y, 32);
                acc.z += __shfl_xor(acc.z, 32);
                acc.w += __shfl_xor(acc.w, 32);
                Z     += __shfl_xor(Z, 32);
                const float invZ = 1.0f / Z;
                acc.x *= invZ; acc.y *= invZ; acc.z *= invZ; acc.w *= invZ;
            }
            if (g == 0)
                *(float4*)&sE[w][c * 4] = acc;   // etilde
        }
    } else {
        // ------------- fallback (nrows > CAP, ~0.4%): direct from HBM ------
        float4 acc = make_float4(0.f, 0.f, 0.f, 0.f);
        float Z = 0.f;
        if (segi < S && n > 0) {
            const float4 qv = *(const float4*)&sQ[w][c * 4];   // log2-scaled
            const float* bp = E + (size_t)r0 * 128 + c * 4;
            for (int rp = 0; rp < nfull; rp += 2) {
                const float4 ev = *(const float4*)(bp + (size_t)(rp + g) * 128);
                float pd = ev.x * qv.x + ev.y * qv.y + ev.z * qv.z + ev.w * qv.w;
                pd = red32_sum(pd);
                const float wgt = exp2f(pd);
                Z += wgt;
                acc.x += wgt * ev.x; acc.y += wgt * ev.y;
                acc.z += wgt * ev.z; acc.w += wgt * ev.w;
            }
            if ((n & 1) && g == 0) {
                const float4 ev = *(const float4*)(bp + (size_t)(n - 1) * 128);
                float pd = ev.x * qv.x + ev.y * qv.y + ev.z * qv.z + ev.w * qv.w;
                pd = red32_sum(pd);
                const float wgt = exp2f(pd);
                Z += wgt;
                acc.x += wgt * ev.x; acc.y += wgt * ev.y;
                acc.z += wgt * ev.z; acc.w += wgt * ev.w;
            }
            acc.x += __shfl_xor(acc.x, 32);
            acc.y += __shfl_xor(acc.y, 32);
            acc.z += __shfl_xor(acc.z, 32);
            acc.w += __shfl_xor(acc.w, 32);
            Z     += __shfl_xor(Z, 32);
            const float invZ = 1.0f / Z;
            acc.x *= invZ; acc.y *= invZ; acc.z *= invZ; acc.w *= invZ;
        }
        if (g == 0)
            *(float4*)&sE[w][c * 4] = acc;
    }
    __syncthreads();                                            // B4

    // ---------------- out GEMM via MFMA: out = sE @ Wt ---------------------
    {
        f32x4 c0 = {0.f, 0.f, 0.f, 0.f};
        f32x4 c1 = {0.f, 0.f, 0.f, 0.f};
        const uint4* Bp = (const uint4*)Wpk;
#pragma unroll
        for (int kt = 0; kt < 4; ++kt) {
            const bf16x8 a = pack_a8(&sE[arow & 3][kt * 32 + akg * 8]);
            union { uint4 u; bf16x8 v; } b0, b1;
            b0.u = Bp[(size_t)(kt * 8 + 2 * w) * 64 + lane];
            b1.u = Bp[(size_t)(kt * 8 + 2 * w + 1) * 64 + lane];
            c0 = __builtin_amdgcn_mfma_f32_16x16x32_bf16(a, b0.v, c0, 0, 0, 0);
            c1 = __builtin_amdgcn_mfma_f32_16x16x32_bf16(a, b1.v, c1, 0, 0, 0);
        }
        if (akg == 0) {
#pragma unroll
            for (int r = 0; r < 4; ++r) {
                const int s = s0 + r;
                if (s < S) {
                    out[(size_t)s * 128 + (2 * w) * 16 + arow]     = c0[r];
                    out[(size_t)s * 128 + (2 * w + 1) * 16 + arow] = c1[r];
                }
            }
        }
    }
}

// ---------------------------------------------------------------------------
extern "C" void kernel_launch(void* const* d_in, const int* in_sizes, int n_in,
                              void* d_out, int out_size, void* d_ws, size_t ws_size,
                              hipStream_t stream) {
    const float* E   = (const float*)d_in[0];
    const int*   map = (const int*)d_in[1];
    const float* Wk  = (const float*)d_in[3];
    const float* Wv  = (const float*)d_in[4];
    const float* Wo  = (const float*)d_in[5];
    float* out = (float*)d_out;

    const int V = in_sizes[1];
    const int S = out_size / 128;

    char* p = (char*)d_ws;
    auto alloc = [&](size_t b) {
        char* r = p;
        p += (b + 255) & ~(size_t)255;
        return r;
    };
    int*            starts = (int*)alloc((size_t)(S + 1) * sizeof(int));
    unsigned short* Mpk    = (unsigned short*)alloc(128 * 128 * sizeof(unsigned short));
    unsigned short* Wpk    = (unsigned short*)alloc(128 * 128 * sizeof(unsigned short));

    k_segstarts<<<(V + 255) / 256, 256, 0, stream>>>(map, starts, V, S);
    k_prep<<<128, 128, 0, stream>>>(Wk, Wv, Wo, Mpk, Wpk);
    k_main<<<(S + G - 1) / G, 256, 0, stream>>>(E, starts, Mpk, Wpk, out, V, S);
}

// Round 19
// 134.415 us; speedup vs baseline: 1.0792x; 1.0792x over previous
//
#include <hip/hip_runtime.h>
#include <math.h>

#define G    4      // segments per block
#define CAP  104    // max staged rows per group (~0.4% fallback)

typedef __attribute__((ext_vector_type(8))) short bf16x8;
typedef __attribute__((ext_vector_type(4))) float f32x4;

// ---------------------------------------------------------------------------
__global__ void k_segstarts(const int* __restrict__ map, int* __restrict__ starts,
                            int V, int S) {
    int i = blockIdx.x * blockDim.x + threadIdx.x;
    if (i >= V) return;
    int cur  = map[i];
    int prev = (i == 0) ? -1 : map[i - 1];
    for (int s = prev + 1; s <= cur; ++s) starts[s] = i;
    if (i == V - 1) {
        for (int s = cur + 1; s <= S; ++s) starts[s] = V;
    }
}

__device__ __forceinline__ unsigned f2bf_rte(float x) {          // RTNE -> top 16
    unsigned b = __float_as_uint(x);
    b += 0x7FFFu + ((b >> 16) & 1u);
    return b >> 16;
}
__device__ __forceinline__ float bfu_lo(unsigned u) {
    return __uint_as_float(u << 16);
}
__device__ __forceinline__ float bfu_hi(unsigned u) {
    return __uint_as_float(u & 0xFFFF0000u);
}

template <int CTRL>
__device__ __forceinline__ float dpp_add(float v) {
    int t = __builtin_amdgcn_update_dpp(0, __float_as_int(v), CTRL, 0xF, 0xF, true);
    return v + __int_as_float(t);
}
// sum across the 16-lane DPP row (pure VALU, no LDS pipe)
__device__ __forceinline__ float red16_sum(float v) {
    v = dpp_add<0xB1>(v);    // quad_perm xor1
    v = dpp_add<0x4E>(v);    // quad_perm xor2
    v = dpp_add<0x141>(v);   // row_half_mirror (combines quads)
    v = dpp_add<0x140>(v);   // row_mirror (combines 8-groups)
    return v;                // all 16 lanes of the row hold the sum
}
// fallback-path 32-lane reduce
__device__ __forceinline__ float red32_sum(float v) {
    v = red16_sum(v);
    v += __int_as_float(__builtin_amdgcn_ds_swizzle(__float_as_int(v), 0x401F));
    return v;
}

// ---------------------------------------------------------------------------
// k_prep: M = (Wk^T Wv) * LOG2E (q pre-scaled for exp2), Wt = Wo^T; both in
// MFMA B-fragment order (bf16): B col = lane&15, k = (lane>>4)*8 + t;
// ushort index = ((f*64 + lane)*8 + t), f = kt*8 + jt.
// ---------------------------------------------------------------------------
__global__ void k_prep(const float* __restrict__ Wk, const float* __restrict__ Wv,
                       const float* __restrict__ Wo,
                       unsigned short* __restrict__ Mpk,
                       unsigned short* __restrict__ Wpk) {
    const int i = blockIdx.x;     // k dim 0..127
    const int j = threadIdx.x;    // col  0..127
    float acc = 0.f;
#pragma unroll 8
    for (int h = 0; h < 128; ++h)
        acc += Wk[h * 128 + i] * Wv[h * 128 + j];
    acc *= 1.4426950408889634f;

    const int kt  = i >> 5;
    const int kg  = (i >> 3) & 3;
    const int t   = i & 7;
    const int jt  = j >> 4;
    const int l16 = j & 15;
    const int lane = kg * 16 + l16;
    const size_t idx = ((size_t)(kt * 8 + jt) * 64 + lane) * 8 + t;
    Mpk[idx] = (unsigned short)f2bf_rte(acc);
    Wpk[idx] = (unsigned short)f2bf_rte(Wo[j * 128 + i]);
}

// pack 8 consecutive fp32 -> bf16x8 (truncation)
__device__ __forceinline__ bf16x8 pack_a8(const float* p) {
    union { unsigned u[4]; bf16x8 v; } r;
    const float4 f0 = *(const float4*)p;
    const float4 f1 = *(const float4*)(p + 4);
    r.u[0] = (__float_as_uint(f0.y) & 0xFFFF0000u) | (__float_as_uint(f0.x) >> 16);
    r.u[1] = (__float_as_uint(f0.w) & 0xFFFF0000u) | (__float_as_uint(f0.z) >> 16);
    r.u[2] = (__float_as_uint(f1.y) & 0xFFFF0000u) | (__float_as_uint(f1.x) >> 16);
    r.u[3] = (__float_as_uint(f1.w) & 0xFFFF0000u) | (__float_as_uint(f1.z) >> 16);
    return r.v;
}

// swizzled within-row uint offset for sA (4-aligned-safe: both terms x4)
__device__ __forceinline__ int swz(int row, int uoff) {
    return uoff ^ ((row & 7) << 2);
}

// ---------------------------------------------------------------------------
// k_main (R16 structure): bf16 E staged once in swizzled LDS; MFMA qGEMM and
// outGEMM; b128-wide sweeps with 16-lane DPP reduces (no per-iter ds_swizzle).
// Phases: stage -B1- mean -B2- qGEMM -B3- attn -B4- outGEMM.
// ---------------------------------------------------------------------------
__global__ __launch_bounds__(256, 4) void k_main(
    const float* __restrict__ E, const int* __restrict__ starts,
    const unsigned short* __restrict__ Mpk, const unsigned short* __restrict__ Wpk,
    float* __restrict__ out, int V, int S)
{
    __shared__ unsigned sA[CAP][64];   // bf16-packed rows, swizzled (26.6 KB)
    __shared__ float    sE[G][128];    // ebar, later etilde (2 KB)
    __shared__ float    sQ[G][128];    // q (2 KB)

    const int tid  = threadIdx.x;
    const int w    = tid >> 6;       // wave id = local segment id
    const int lane = tid & 63;
    const int s0   = blockIdx.x * G;

    const int se    = min(s0 + G, S);
    const int gr0   = starts[s0];
    const int nrows = starts[se] - gr0;
    const bool staged = (nrows <= CAP);

    const int c  = lane & 31;        // fallback: column quad
    const int g  = lane >> 5;        // fallback: row parity
    const int c8 = lane & 15;        // staged sweeps: column octet
    const int g2 = lane >> 4;        // staged sweeps: row-in-quad 0..3

    // ---------------- stage: E rows -> swizzled bf16 LDS (5/5/3) -----------
    if (staged && nrows > 0) {
        const int q4 = tid & 31;
        const int rr = tid >> 5;                 // 0..7, stride 8
        const float* gp = E + (size_t)gr0 * 128 + q4 * 4;
#pragma unroll
        for (int b = 0; b < 3; ++b) {
            const int nb = (b == 2) ? 3 : 5;
            const int k0 = b * 5;
            float4 t[5];
            for (int k = 0; k < nb; ++k) {
                const int r = min(rr + (k0 + k) * 8, nrows - 1);   // clamp: dup
                t[k] = *(const float4*)(gp + (size_t)r * 128);
            }
            for (int k = 0; k < nb; ++k) {
                const int row = rr + (k0 + k) * 8;
                uint2 u;
                u.x = f2bf_rte(t[k].x) | (f2bf_rte(t[k].y) << 16);
                u.y = f2bf_rte(t[k].z) | (f2bf_rte(t[k].w) << 16);
                *(uint2*)&sA[row][swz(row, q4 * 2)] = u;           // dup unread
            }
        }
    }
    __syncthreads();                                            // B1

    // per-wave segment meta
    const int segi = s0 + w;
    int r0 = 0, n = 0, off = 0;
    if (segi < S) {
        r0  = starts[segi];
        n   = starts[segi + 1] - r0;
        off = r0 - gr0;
    }
    const int nq   = n & ~3;
    const int nrem = n & 3;

    // ---------------- mean: ebar[w] ----------------------------------------
    {
        float4 sumA = make_float4(0.f, 0.f, 0.f, 0.f);
        float4 sumB = make_float4(0.f, 0.f, 0.f, 0.f);
        if (segi < S && n > 0) {
            if (staged) {
                for (int q = 0; q < nq; q += 4) {
                    const int row = off + q + g2;
                    const uint4 u = *(const uint4*)&sA[row][swz(row, c8 * 4)];
                    sumA.x += bfu_lo(u.x); sumA.y += bfu_hi(u.x);
                    sumA.z += bfu_lo(u.y); sumA.w += bfu_hi(u.y);
                    sumB.x += bfu_lo(u.z); sumB.y += bfu_hi(u.z);
                    sumB.z += bfu_lo(u.w); sumB.w += bfu_hi(u.w);
                }
                if (g2 < nrem) {
                    const int row = off + nq + g2;
                    const uint4 u = *(const uint4*)&sA[row][swz(row, c8 * 4)];
                    sumA.x += bfu_lo(u.x); sumA.y += bfu_hi(u.x);
                    sumA.z += bfu_lo(u.y); sumA.w += bfu_hi(u.y);
                    sumB.x += bfu_lo(u.z); sumB.y += bfu_hi(u.z);
                    sumB.z += bfu_lo(u.w); sumB.w += bfu_hi(u.w);
                }
            } else {
                const float* bp = E + (size_t)r0 * 128 + c8 * 8;
                for (int q = 0; q < nq; q += 4) {
                    const float4 e0 = *(const float4*)(bp + (size_t)(q + g2) * 128);
                    const float4 e1 = *(const float4*)(bp + (size_t)(q + g2) * 128 + 4);
                    sumA.x += e0.x; sumA.y += e0.y; sumA.z += e0.z; sumA.w += e0.w;
                    sumB.x += e1.x; sumB.y += e1.y; sumB.z += e1.z; sumB.w += e1.w;
                }
                if (g2 < nrem) {
                    const float4 e0 = *(const float4*)(bp + (size_t)(nq + g2) * 128);
                    const float4 e1 = *(const float4*)(bp + (size_t)(nq + g2) * 128 + 4);
                    sumA.x += e0.x; sumA.y += e0.y; sumA.z += e0.z; sumA.w += e0.w;
                    sumB.x += e1.x; sumB.y += e1.y; sumB.z += e1.z; sumB.w += e1.w;
                }
            }
            // combine across the 4 row-groups
            float* sf = (float*)&sumA;
#pragma unroll
            for (int k = 0; k < 4; ++k) {
                sf[k] += __shfl_xor(sf[k], 16);
                sf[k] += __shfl_xor(sf[k], 32);
            }
            float* sg = (float*)&sumB;
#pragma unroll
            for (int k = 0; k < 4; ++k) {
                sg[k] += __shfl_xor(sg[k], 16);
                sg[k] += __shfl_xor(sg[k], 32);
            }
            const float inv = 1.0f / (float)n;
            sumA.x *= inv; sumA.y *= inv; sumA.z *= inv; sumA.w *= inv;
            sumB.x *= inv; sumB.y *= inv; sumB.z *= inv; sumB.w *= inv;
        }
        if (g2 == 0) {
            *(float4*)&sE[w][c8 * 8]     = sumA;   // zeros if empty/out-of-range
            *(float4*)&sE[w][c8 * 8 + 4] = sumB;
        }
    }
    __syncthreads();                                            // B2

    // ---------------- q GEMM via MFMA: sQ = sE @ M -------------------------
    const int arow = lane & 15;       // A row / C col
    const int akg  = lane >> 4;       // k-group
    {
        f32x4 c0 = {0.f, 0.f, 0.f, 0.f};
        f32x4 c1 = {0.f, 0.f, 0.f, 0.f};
        const uint4* Bp = (const uint4*)Mpk;
#pragma unroll
        for (int kt = 0; kt < 4; ++kt) {
            const bf16x8 a = pack_a8(&sE[arow & 3][kt * 32 + akg * 8]);
            union { uint4 u; bf16x8 v; } b0, b1;
            b0.u = Bp[(size_t)(kt * 8 + 2 * w) * 64 + lane];
            b1.u = Bp[(size_t)(kt * 8 + 2 * w + 1) * 64 + lane];
            c0 = __builtin_amdgcn_mfma_f32_16x16x32_bf16(a, b0.v, c0, 0, 0, 0);
            c1 = __builtin_amdgcn_mfma_f32_16x16x32_bf16(a, b1.v, c1, 0, 0, 0);
        }
        if (akg == 0) {                       // C rows 0-3 live in lanes 0-15
#pragma unroll
            for (int r = 0; r < 4; ++r) {
                sQ[r][(2 * w) * 16 + arow]     = c0[r];
                sQ[r][(2 * w + 1) * 16 + arow] = c1[r];
            }
        }
    }
    __syncthreads();                                            // B3

    // ---------------- attn: scores + exp2 + weighted sum -------------------
    if (staged) {
        float4 accA = make_float4(0.f, 0.f, 0.f, 0.f);
        float4 accB = make_float4(0.f, 0.f, 0.f, 0.f);
        float Z = 0.f;
        if (segi < S && n > 0) {
            const float4 qA = *(const float4*)&sQ[w][c8 * 8];      // log2-scaled
            const float4 qB = *(const float4*)&sQ[w][c8 * 8 + 4];
            for (int q = 0; q < nq; q += 4) {
                const int row = off + q + g2;
                const uint4 u = *(const uint4*)&sA[row][swz(row, c8 * 4)];
                const float e0 = bfu_lo(u.x), e1 = bfu_hi(u.x);
                const float e2 = bfu_lo(u.y), e3 = bfu_hi(u.y);
                const float e4 = bfu_lo(u.z), e5 = bfu_hi(u.z);
                const float e6 = bfu_lo(u.w), e7 = bfu_hi(u.w);
                float pd = e0 * qA.x + e1 * qA.y + e2 * qA.z + e3 * qA.w
                         + e4 * qB.x + e5 * qB.y + e6 * qB.z + e7 * qB.w;
                pd = red16_sum(pd);            // full row dot, 4 DPP adds
                const float wgt = exp2f(pd);
                Z += wgt;
                accA.x += wgt * e0; accA.y += wgt * e1;
                accA.z += wgt * e2; accA.w += wgt * e3;
                accB.x += wgt * e4; accB.y += wgt * e5;
                accB.z += wgt * e6; accB.w += wgt * e7;
            }
            if (g2 < nrem) {                   // group-uniform mask: DPP safe
                const int row = off + nq + g2;
                const uint4 u = *(const uint4*)&sA[row][swz(row, c8 * 4)];
                const float e0 = bfu_lo(u.x), e1 = bfu_hi(u.x);
                const float e2 = bfu_lo(u.y), e3 = bfu_hi(u.y);
                const float e4 = bfu_lo(u.z), e5 = bfu_hi(u.z);
                const float e6 = bfu_lo(u.w), e7 = bfu_hi(u.w);
                float pd = e0 * qA.x + e1 * qA.y + e2 * qA.z + e3 * qA.w
                         + e4 * qB.x + e5 * qB.y + e6 * qB.z + e7 * qB.w;
                pd = red16_sum(pd);
                const float wgt = exp2f(pd);
                Z += wgt;
                accA.x += wgt * e0; accA.y += wgt * e1;
                accA.z += wgt * e2; accA.w += wgt * e3;
                accB.x += wgt * e4; accB.y += wgt * e5;
                accB.z += wgt * e6; accB.w += wgt * e7;
            }
            float* af = (float*)&accA;
#pragma unroll
            for (int k = 0; k < 4; ++k) {
                af[k] += __shfl_xor(af[k], 16);
                af[k] += __shfl_xor(af[k], 32);
            }
            float* ag = (float*)&accB;
#pragma unroll
            for (int k = 0; k < 4; ++k) {
                ag[k] += __shfl_xor(ag[k], 16);
                ag[k] += __shfl_xor(ag[k], 32);
            }
            Z += __shfl_xor(Z, 16);
            Z += __shfl_xor(Z, 32);
            const float invZ = 1.0f / Z;
            accA.x *= invZ; accA.y *= invZ; accA.z *= invZ; accA.w *= invZ;
            accB.x *= invZ; accB.y *= invZ; accB.z *= invZ; accB.w *= invZ;
        }
        if (g2 == 0) {
            *(float4*)&sE[w][c8 * 8]     = accA;   // etilde (zeros if empty)
            *(float4*)&sE[w][c8 * 8 + 4] = accB;
        }
    } else {
        // ------------- fallback (nrows > CAP, ~0.4%): direct from HBM ------
        float4 acc = make_float4(0.f, 0.f, 0.f, 0.f);
        float Z = 0.f;
        if (segi < S && n > 0) {
            const float4 qv = *(const float4*)&sQ[w][c * 4];   // log2-scaled
            const float* bp = E + (size_t)r0 * 128 + c * 4;
            const int nfull = n & ~1;
            for (int rp = 0; rp < nfull; rp += 2) {
                const float4 ev = *(const float4*)(bp + (size_t)(rp + g) * 128);
                float pd = ev.x * qv.x + ev.y * qv.y + ev.z * qv.z + ev.w * qv.w;
                pd = red32_sum(pd);
                const float wgt = exp2f(pd);
                Z += wgt;
                acc.x += wgt * ev.x; acc.y += wgt * ev.y;
                acc.z += wgt * ev.z; acc.w += wgt * ev.w;
            }
            if ((n & 1) && g == 0) {
                const float4 ev = *(const float4*)(bp + (size_t)(n - 1) * 128);
                float pd = ev.x * qv.x + ev.y * qv.y + ev.z * qv.z + ev.w * qv.w;
                pd = red32_sum(pd);
                const float wgt = exp2f(pd);
                Z += wgt;
                acc.x += wgt * ev.x; acc.y += wgt * ev.y;
                acc.z += wgt * ev.z; acc.w += wgt * ev.w;
            }
            acc.x += __shfl_xor(acc.x, 32);
            acc.y += __shfl_xor(acc.y, 32);
            acc.z += __shfl_xor(acc.z, 32);
            acc.w += __shfl_xor(acc.w, 32);
            Z     += __shfl_xor(Z, 32);
            const float invZ = 1.0f / Z;
            acc.x *= invZ; acc.y *= invZ; acc.z *= invZ; acc.w *= invZ;
        }
        if (g == 0)
            *(float4*)&sE[w][c * 4] = acc;
    }
    __syncthreads();                                            // B4

    // ---------------- out GEMM via MFMA: out = sE @ Wt ---------------------
    {
        f32x4 c0 = {0.f, 0.f, 0.f, 0.f};
        f32x4 c1 = {0.f, 0.f, 0.f, 0.f};
        const uint4* Bp = (const uint4*)Wpk;
#pragma unroll
        for (int kt = 0; kt < 4; ++kt) {
            const bf16x8 a = pack_a8(&sE[arow & 3][kt * 32 + akg * 8]);
            union { uint4 u; bf16x8 v; } b0, b1;
            b0.u = Bp[(size_t)(kt * 8 + 2 * w) * 64 + lane];
            b1.u = Bp[(size_t)(kt * 8 + 2 * w + 1) * 64 + lane];
            c0 = __builtin_amdgcn_mfma_f32_16x16x32_bf16(a, b0.v, c0, 0, 0, 0);
            c1 = __builtin_amdgcn_mfma_f32_16x16x32_bf16(a, b1.v, c1, 0, 0, 0);
        }
        if (akg == 0) {
#pragma unroll
            for (int r = 0; r < 4; ++r) {
                const int s = s0 + r;
                if (s < S) {
                    out[(size_t)s * 128 + (2 * w) * 16 + arow]     = c0[r];
                    out[(size_t)s * 128 + (2 * w + 1) * 16 + arow] = c1[r];
                }
            }
        }
    }
}

// ---------------------------------------------------------------------------
extern "C" void kernel_launch(void* const* d_in, const int* in_sizes, int n_in,
                              void* d_out, int out_size, void* d_ws, size_t ws_size,
                              hipStream_t stream) {
    const float* E   = (const float*)d_in[0];
    const int*   map = (const int*)d_in[1];
    const float* Wk  = (const float*)d_in[3];
    const float* Wv  = (const float*)d_in[4];
    const float* Wo  = (const float*)d_in[5];
    float* out = (float*)d_out;

    const int V = in_sizes[1];
    const int S = out_size / 128;

    char* p = (char*)d_ws;
    auto alloc = [&](size_t b) {
        char* r = p;
        p += (b + 255) & ~(size_t)255;
        return r;
    };
    int*            starts = (int*)alloc((size_t)(S + 1) * sizeof(int));
    unsigned short* Mpk    = (unsigned short*)alloc(128 * 128 * sizeof(unsigned short));
    unsigned short* Wpk    = (unsigned short*)alloc(128 * 128 * sizeof(unsigned short));

    k_segstarts<<<(V + 255) / 256, 256, 0, stream>>>(map, starts, V, S);
    k_prep<<<128, 128, 0, stream>>>(Wk, Wv, Wo, Mpk, Wpk);
    k_main<<<(S + G - 1) / G, 256, 0, stream>>>(E, starts, Mpk, Wpk, out, V, S);
}

// Round 20
// 131.033 us; speedup vs baseline: 1.1070x; 1.0258x over previous
//
#include <hip/hip_runtime.h>
#include <math.h>

#define G    4      // segments per block
#define CAP  104    // max staged rows per group (~0.4% fallback)

typedef __attribute__((ext_vector_type(8))) short bf16x8;
typedef __attribute__((ext_vector_type(4))) float f32x4;

#if __has_builtin(__builtin_amdgcn_fdot2_f32_bf16)
#define HAVE_DOT2 1
typedef __attribute__((ext_vector_type(2))) __bf16 bf16x2;
__device__ __forceinline__ float dot2bf(unsigned eu, unsigned qu, float c) {
    union { unsigned u; bf16x2 v; } a, b;
    a.u = eu; b.u = qu;
    return __builtin_amdgcn_fdot2_f32_bf16(a.v, b.v, c, false);
}
#endif

__device__ __forceinline__ unsigned f2bf_rte(float x) {          // RTNE -> top 16
    unsigned b = __float_as_uint(x);
    b += 0x7FFFu + ((b >> 16) & 1u);
    return b >> 16;
}
__device__ __forceinline__ float bfu_lo(unsigned u) {
    return __uint_as_float(u << 16);
}
__device__ __forceinline__ float bfu_hi(unsigned u) {
    return __uint_as_float(u & 0xFFFF0000u);
}

template <int CTRL>
__device__ __forceinline__ float dpp_add(float v) {
    int t = __builtin_amdgcn_update_dpp(0, __float_as_int(v), CTRL, 0xF, 0xF, true);
    return v + __int_as_float(t);
}
// sum across the 16-lane DPP row (pure VALU, no LDS pipe)
__device__ __forceinline__ float red16_sum(float v) {
    v = dpp_add<0xB1>(v);    // quad_perm xor1
    v = dpp_add<0x4E>(v);    // quad_perm xor2
    v = dpp_add<0x141>(v);   // row_half_mirror
    v = dpp_add<0x140>(v);   // row_mirror
    return v;
}
// fallback-path 32-lane reduce
__device__ __forceinline__ float red32_sum(float v) {
    v = red16_sum(v);
    v += __int_as_float(__builtin_amdgcn_ds_swizzle(__float_as_int(v), 0x401F));
    return v;
}

// ---------------------------------------------------------------------------
// k_pre: fused prologue. Blocks [0,nsb): seg_starts. Blocks [nsb,nsb+64):
// M = (Wk^T Wv)*LOG2E and Wt = Wo^T, stored in MFMA B-fragment order (bf16):
// B col = lane&15, k = (lane>>4)*8 + t; ushort idx = ((f*64+lane)*8+t),
// f = kt*8 + jt.
// ---------------------------------------------------------------------------
__global__ void k_pre(const int* __restrict__ map, int* __restrict__ starts,
                      const float* __restrict__ Wk, const float* __restrict__ Wv,
                      const float* __restrict__ Wo,
                      unsigned short* __restrict__ Mpk,
                      unsigned short* __restrict__ Wpk,
                      int V, int S, int nsb) {
    const int bid = blockIdx.x;
    if (bid < nsb) {
        const int i = bid * 256 + threadIdx.x;
        if (i >= V) return;
        const int cur  = map[i];
        const int prev = (i == 0) ? -1 : map[i - 1];
        for (int s = prev + 1; s <= cur; ++s) starts[s] = i;
        if (i == V - 1) {
            for (int s = cur + 1; s <= S; ++s) starts[s] = V;
        }
    } else {
        const int i = (bid - nsb) * 2 + (threadIdx.x >> 7);   // k-dim 0..127
        const int j = threadIdx.x & 127;                      // col   0..127
        float acc = 0.f;
#pragma unroll 8
        for (int h = 0; h < 128; ++h)
            acc += Wk[h * 128 + i] * Wv[h * 128 + j];
        acc *= 1.4426950408889634f;   // LOG2E baked -> exp2 in attn

        const int kt  = i >> 5;
        const int kg  = (i >> 3) & 3;
        const int t   = i & 7;
        const int jt  = j >> 4;
        const int l16 = j & 15;
        const int lane = kg * 16 + l16;
        const size_t idx = ((size_t)(kt * 8 + jt) * 64 + lane) * 8 + t;
        Mpk[idx] = (unsigned short)f2bf_rte(acc);
        Wpk[idx] = (unsigned short)f2bf_rte(Wo[j * 128 + i]);
    }
}

// pack 8 consecutive fp32 -> bf16x8 (truncation)
__device__ __forceinline__ bf16x8 pack_a8(const float* p) {
    union { unsigned u[4]; bf16x8 v; } r;
    const float4 f0 = *(const float4*)p;
    const float4 f1 = *(const float4*)(p + 4);
    r.u[0] = (__float_as_uint(f0.y) & 0xFFFF0000u) | (__float_as_uint(f0.x) >> 16);
    r.u[1] = (__float_as_uint(f0.w) & 0xFFFF0000u) | (__float_as_uint(f0.z) >> 16);
    r.u[2] = (__float_as_uint(f1.y) & 0xFFFF0000u) | (__float_as_uint(f1.x) >> 16);
    r.u[3] = (__float_as_uint(f1.w) & 0xFFFF0000u) | (__float_as_uint(f1.z) >> 16);
    return r.v;
}

// swizzled within-row uint offset for sA (4-aligned-safe: both terms x4)
__device__ __forceinline__ int swz(int row, int uoff) {
    return uoff ^ ((row & 7) << 2);
}

// ---------------------------------------------------------------------------
// k_main (R19 structure): bf16 E staged once in swizzled LDS; MFMA qGEMM and
// outGEMM; b128-wide sweeps, 16-lane DPP reduces; attn dot via v_dot2 bf16.
// Phases: stage -B1- mean -B2- qGEMM -B3- attn -B4- outGEMM.
// ---------------------------------------------------------------------------
__global__ __launch_bounds__(256, 4) void k_main(
    const float* __restrict__ E, const int* __restrict__ starts,
    const unsigned short* __restrict__ Mpk, const unsigned short* __restrict__ Wpk,
    float* __restrict__ out, int V, int S)
{
    __shared__ unsigned sA[CAP][64];   // bf16-packed rows, swizzled (26.6 KB)
    __shared__ float    sE[G][128];    // ebar, later etilde (2 KB)
    __shared__ float    sQ[G][128];    // q (2 KB)

    const int tid  = threadIdx.x;
    const int w    = tid >> 6;       // wave id = local segment id
    const int lane = tid & 63;
    const int s0   = blockIdx.x * G;

    const int se    = min(s0 + G, S);
    const int gr0   = starts[s0];
    const int nrows = starts[se] - gr0;
    const bool staged = (nrows <= CAP);

    const int c  = lane & 31;        // fallback: column quad
    const int g  = lane >> 5;        // fallback: row parity
    const int c8 = lane & 15;        // staged sweeps: column octet
    const int g2 = lane >> 4;        // staged sweeps: row-in-quad 0..3

    // ---------------- stage: E rows -> swizzled bf16 LDS (5/5/3) -----------
    if (staged && nrows > 0) {
        const int q4 = tid & 31;
        const int rr = tid >> 5;                 // 0..7, stride 8
        const float* gp = E + (size_t)gr0 * 128 + q4 * 4;
#pragma unroll
        for (int b = 0; b < 3; ++b) {
            const int nb = (b == 2) ? 3 : 5;
            const int k0 = b * 5;
            float4 t[5];
            for (int k = 0; k < nb; ++k) {
                const int r = min(rr + (k0 + k) * 8, nrows - 1);   // clamp: dup
                t[k] = *(const float4*)(gp + (size_t)r * 128);
            }
            for (int k = 0; k < nb; ++k) {
                const int row = rr + (k0 + k) * 8;
                uint2 u;
                u.x = f2bf_rte(t[k].x) | (f2bf_rte(t[k].y) << 16);
                u.y = f2bf_rte(t[k].z) | (f2bf_rte(t[k].w) << 16);
                *(uint2*)&sA[row][swz(row, q4 * 2)] = u;           // dup unread
            }
        }
    }
    __syncthreads();                                            // B1

    // per-wave segment meta
    const int segi = s0 + w;
    int r0 = 0, n = 0, off = 0;
    if (segi < S) {
        r0  = starts[segi];
        n   = starts[segi + 1] - r0;
        off = r0 - gr0;
    }
    const int nq   = n & ~3;
    const int nrem = n & 3;

    // ---------------- mean: ebar[w] ----------------------------------------
    {
        float4 sumA = make_float4(0.f, 0.f, 0.f, 0.f);
        float4 sumB = make_float4(0.f, 0.f, 0.f, 0.f);
        if (segi < S && n > 0) {
            if (staged) {
                for (int q = 0; q < nq; q += 4) {
                    const int row = off + q + g2;
                    const uint4 u = *(const uint4*)&sA[row][swz(row, c8 * 4)];
                    sumA.x += bfu_lo(u.x); sumA.y += bfu_hi(u.x);
                    sumA.z += bfu_lo(u.y); sumA.w += bfu_hi(u.y);
                    sumB.x += bfu_lo(u.z); sumB.y += bfu_hi(u.z);
                    sumB.z += bfu_lo(u.w); sumB.w += bfu_hi(u.w);
                }
                if (g2 < nrem) {
                    const int row = off + nq + g2;
                    const uint4 u = *(const uint4*)&sA[row][swz(row, c8 * 4)];
                    sumA.x += bfu_lo(u.x); sumA.y += bfu_hi(u.x);
                    sumA.z += bfu_lo(u.y); sumA.w += bfu_hi(u.y);
                    sumB.x += bfu_lo(u.z); sumB.y += bfu_hi(u.z);
                    sumB.z += bfu_lo(u.w); sumB.w += bfu_hi(u.w);
                }
            } else {
                const float* bp = E + (size_t)r0 * 128 + c8 * 8;
                for (int q = 0; q < nq; q += 4) {
                    const float4 e0 = *(const float4*)(bp + (size_t)(q + g2) * 128);
                    const float4 e1 = *(const float4*)(bp + (size_t)(q + g2) * 128 + 4);
                    sumA.x += e0.x; sumA.y += e0.y; sumA.z += e0.z; sumA.w += e0.w;
                    sumB.x += e1.x; sumB.y += e1.y; sumB.z += e1.z; sumB.w += e1.w;
                }
                if (g2 < nrem) {
                    const float4 e0 = *(const float4*)(bp + (size_t)(nq + g2) * 128);
                    const float4 e1 = *(const float4*)(bp + (size_t)(nq + g2) * 128 + 4);
                    sumA.x += e0.x; sumA.y += e0.y; sumA.z += e0.z; sumA.w += e0.w;
                    sumB.x += e1.x; sumB.y += e1.y; sumB.z += e1.z; sumB.w += e1.w;
                }
            }
            float* sf = (float*)&sumA;
#pragma unroll
            for (int k = 0; k < 4; ++k) {
                sf[k] += __shfl_xor(sf[k], 16);
                sf[k] += __shfl_xor(sf[k], 32);
            }
            float* sg = (float*)&sumB;
#pragma unroll
            for (int k = 0; k < 4; ++k) {
                sg[k] += __shfl_xor(sg[k], 16);
                sg[k] += __shfl_xor(sg[k], 32);
            }
            const float inv = 1.0f / (float)n;
            sumA.x *= inv; sumA.y *= inv; sumA.z *= inv; sumA.w *= inv;
            sumB.x *= inv; sumB.y *= inv; sumB.z *= inv; sumB.w *= inv;
        }
        if (g2 == 0) {
            *(float4*)&sE[w][c8 * 8]     = sumA;
            *(float4*)&sE[w][c8 * 8 + 4] = sumB;
        }
    }
    __syncthreads();                                            // B2

    // ---------------- q GEMM via MFMA: sQ = sE @ M -------------------------
    const int arow = lane & 15;       // A row / C col
    const int akg  = lane >> 4;       // k-group
    {
        f32x4 c0 = {0.f, 0.f, 0.f, 0.f};
        f32x4 c1 = {0.f, 0.f, 0.f, 0.f};
        const uint4* Bp = (const uint4*)Mpk;
#pragma unroll
        for (int kt = 0; kt < 4; ++kt) {
            const bf16x8 a = pack_a8(&sE[arow & 3][kt * 32 + akg * 8]);
            union { uint4 u; bf16x8 v; } b0, b1;
            b0.u = Bp[(size_t)(kt * 8 + 2 * w) * 64 + lane];
            b1.u = Bp[(size_t)(kt * 8 + 2 * w + 1) * 64 + lane];
            c0 = __builtin_amdgcn_mfma_f32_16x16x32_bf16(a, b0.v, c0, 0, 0, 0);
            c1 = __builtin_amdgcn_mfma_f32_16x16x32_bf16(a, b1.v, c1, 0, 0, 0);
        }
        if (akg == 0) {                       // C rows 0-3 live in lanes 0-15
#pragma unroll
            for (int r = 0; r < 4; ++r) {
                sQ[r][(2 * w) * 16 + arow]     = c0[r];
                sQ[r][(2 * w + 1) * 16 + arow] = c1[r];
            }
        }
    }
    __syncthreads();                                            // B3

    // ---------------- attn: scores + exp2 + weighted sum -------------------
    if (staged) {
        float4 accA = make_float4(0.f, 0.f, 0.f, 0.f);
        float4 accB = make_float4(0.f, 0.f, 0.f, 0.f);
        float Z = 0.f;
        if (segi < S && n > 0) {
            const float4 qA = *(const float4*)&sQ[w][c8 * 8];      // log2-scaled
            const float4 qB = *(const float4*)&sQ[w][c8 * 8 + 4];
#if HAVE_DOT2
            uint4 qp;   // q packed to bf16 pairs (once per wave)
            qp.x = f2bf_rte(qA.x) | (f2bf_rte(qA.y) << 16);
            qp.y = f2bf_rte(qA.z) | (f2bf_rte(qA.w) << 16);
            qp.z = f2bf_rte(qB.x) | (f2bf_rte(qB.y) << 16);
            qp.w = f2bf_rte(qB.z) | (f2bf_rte(qB.w) << 16);
#endif
            for (int q = 0; q < nq; q += 4) {
                const int row = off + q + g2;
                const uint4 u = *(const uint4*)&sA[row][swz(row, c8 * 4)];
                const float e0 = bfu_lo(u.x), e1 = bfu_hi(u.x);
                const float e2 = bfu_lo(u.y), e3 = bfu_hi(u.y);
                const float e4 = bfu_lo(u.z), e5 = bfu_hi(u.z);
                const float e6 = bfu_lo(u.w), e7 = bfu_hi(u.w);
#if HAVE_DOT2
                float pd = dot2bf(u.w, qp.w,
                           dot2bf(u.z, qp.z,
                           dot2bf(u.y, qp.y,
                           dot2bf(u.x, qp.x, 0.f))));
#else
                float pd = e0 * qA.x + e1 * qA.y + e2 * qA.z + e3 * qA.w
                         + e4 * qB.x + e5 * qB.y + e6 * qB.z + e7 * qB.w;
#endif
                pd = red16_sum(pd);
                const float wgt = exp2f(pd);
                Z += wgt;
                accA.x += wgt * e0; accA.y += wgt * e1;
                accA.z += wgt * e2; accA.w += wgt * e3;
                accB.x += wgt * e4; accB.y += wgt * e5;
                accB.z += wgt * e6; accB.w += wgt * e7;
            }
            if (g2 < nrem) {                   // group-uniform mask: DPP safe
                const int row = off + nq + g2;
                const uint4 u = *(const uint4*)&sA[row][swz(row, c8 * 4)];
                const float e0 = bfu_lo(u.x), e1 = bfu_hi(u.x);
                const float e2 = bfu_lo(u.y), e3 = bfu_hi(u.y);
                const float e4 = bfu_lo(u.z), e5 = bfu_hi(u.z);
                const float e6 = bfu_lo(u.w), e7 = bfu_hi(u.w);
#if HAVE_DOT2
                float pd = dot2bf(u.w, qp.w,
                           dot2bf(u.z, qp.z,
                           dot2bf(u.y, qp.y,
                           dot2bf(u.x, qp.x, 0.f))));
#else
                float pd = e0 * qA.x + e1 * qA.y + e2 * qA.z + e3 * qA.w
                         + e4 * qB.x + e5 * qB.y + e6 * qB.z + e7 * qB.w;
#endif
                pd = red16_sum(pd);
                const float wgt = exp2f(pd);
                Z += wgt;
                accA.x += wgt * e0; accA.y += wgt * e1;
                accA.z += wgt * e2; accA.w += wgt * e3;
                accB.x += wgt * e4; accB.y += wgt * e5;
                accB.z += wgt * e6; accB.w += wgt * e7;
            }
            float* af = (float*)&accA;
#pragma unroll
            for (int k = 0; k < 4; ++k) {
                af[k] += __shfl_xor(af[k], 16);
                af[k] += __shfl_xor(af[k], 32);
            }
            float* ag = (float*)&accB;
#pragma unroll
            for (int k = 0; k < 4; ++k) {
                ag[k] += __shfl_xor(ag[k], 16);
                ag[k] += __shfl_xor(ag[k], 32);
            }
            Z += __shfl_xor(Z, 16);
            Z += __shfl_xor(Z, 32);
            const float invZ = 1.0f / Z;
            accA.x *= invZ; accA.y *= invZ; accA.z *= invZ; accA.w *= invZ;
            accB.x *= invZ; accB.y *= invZ; accB.z *= invZ; accB.w *= invZ;
        }
        if (g2 == 0) {
            *(float4*)&sE[w][c8 * 8]     = accA;   // etilde (zeros if empty)
            *(float4*)&sE[w][c8 * 8 + 4] = accB;
        }
    } else {
        // ------------- fallback (nrows > CAP, ~0.4%): direct from HBM ------
        float4 acc = make_float4(0.f, 0.f, 0.f, 0.f);
        float Z = 0.f;
        if (segi < S && n > 0) {
            const float4 qv = *(const float4*)&sQ[w][c * 4];   // log2-scaled
            const float* bp = E + (size_t)r0 * 128 + c * 4;
            const int nfull = n & ~1;
            for (int rp = 0; rp < nfull; rp += 2) {
                const float4 ev = *(const float4*)(bp + (size_t)(rp + g) * 128);
                float pd = ev.x * qv.x + ev.y * qv.y + ev.z * qv.z + ev.w * qv.w;
                pd = red32_sum(pd);
                const float wgt = exp2f(pd);
                Z += wgt;
                acc.x += wgt * ev.x; acc.y += wgt * ev.y;
                acc.z += wgt * ev.z; acc.w += wgt * ev.w;
            }
            if ((n & 1) && g == 0) {
                const float4 ev = *(const float4*)(bp + (size_t)(n - 1) * 128);
                float pd = ev.x * qv.x + ev.y * qv.y + ev.z * qv.z + ev.w * qv.w;
                pd = red32_sum(pd);
                const float wgt = exp2f(pd);
                Z += wgt;
                acc.x += wgt * ev.x; acc.y += wgt * ev.y;
                acc.z += wgt * ev.z; acc.w += wgt * ev.w;
            }
            acc.x += __shfl_xor(acc.x, 32);
            acc.y += __shfl_xor(acc.y, 32);
            acc.z += __shfl_xor(acc.z, 32);
            acc.w += __shfl_xor(acc.w, 32);
            Z     += __shfl_xor(Z, 32);
            const float invZ = 1.0f / Z;
            acc.x *= invZ; acc.y *= invZ; acc.z *= invZ; acc.w *= invZ;
        }
        if (g == 0)
            *(float4*)&sE[w][c * 4] = acc;
    }
    __syncthreads();                                            // B4

    // ---------------- out GEMM via MFMA: out = sE @ Wt ---------------------
    {
        f32x4 c0 = {0.f, 0.f, 0.f, 0.f};
        f32x4 c1 = {0.f, 0.f, 0.f, 0.f};
        const uint4* Bp = (const uint4*)Wpk;
#pragma unroll
        for (int kt = 0; kt < 4; ++kt) {
            const bf16x8 a = pack_a8(&sE[arow & 3][kt * 32 + akg * 8]);
            union { uint4 u; bf16x8 v; } b0, b1;
            b0.u = Bp[(size_t)(kt * 8 + 2 * w) * 64 + lane];
            b1.u = Bp[(size_t)(kt * 8 + 2 * w + 1) * 64 + lane];
            c0 = __builtin_amdgcn_mfma_f32_16x16x32_bf16(a, b0.v, c0, 0, 0, 0);
            c1 = __builtin_amdgcn_mfma_f32_16x16x32_bf16(a, b1.v, c1, 0, 0, 0);
        }
        if (akg == 0) {
#pragma unroll
            for (int r = 0; r < 4; ++r) {
                const int s = s0 + r;
                if (s < S) {
                    out[(size_t)s * 128 + (2 * w) * 16 + arow]     = c0[r];
                    out[(size_t)s * 128 + (2 * w + 1) * 16 + arow] = c1[r];
                }
            }
        }
    }
}

// ---------------------------------------------------------------------------
extern "C" void kernel_launch(void* const* d_in, const int* in_sizes, int n_in,
                              void* d_out, int out_size, void* d_ws, size_t ws_size,
                              hipStream_t stream) {
    const float* E   = (const float*)d_in[0];
    const int*   map = (const int*)d_in[1];
    const float* Wk  = (const float*)d_in[3];
    const float* Wv  = (const float*)d_in[4];
    const float* Wo  = (const float*)d_in[5];
    float* out = (float*)d_out;

    const int V = in_sizes[1];
    const int S = out_size / 128;

    char* p = (char*)d_ws;
    auto alloc = [&](size_t b) {
        char* r = p;
        p += (b + 255) & ~(size_t)255;
        return r;
    };
    int*            starts = (int*)alloc((size_t)(S + 1) * sizeof(int));
    unsigned short* Mpk    = (unsigned short*)alloc(128 * 128 * sizeof(unsigned short));
    unsigned short* Wpk    = (unsigned short*)alloc(128 * 128 * sizeof(unsigned short));

    const int nsb = (V + 255) / 256;
    k_pre<<<nsb + 64, 256, 0, stream>>>(map, starts, Wk, Wv, Wo, Mpk, Wpk, V, S, nsb);
    k_main<<<(S + G - 1) / G, 256, 0, stream>>>(E, starts, Mpk, Wpk, out, V, S);
}